// Round 7
// baseline (164.713 us; speedup 1.0000x reference)
//
#include <hip/hip_runtime.h>

// ---------- types / helpers ----------
typedef _Float16 f16x8 __attribute__((ext_vector_type(8)));
typedef float f32x4 __attribute__((ext_vector_type(4)));

__device__ __forceinline__ float tanh_fast(float x){
  // tanh(x) = 1 - 2/(1+exp2(2*log2e*x)); exact at saturation
  float e = __builtin_amdgcn_exp2f(x * 2.88539008177793f);
  return 1.f - 2.f * __builtin_amdgcn_rcpf(1.f + e);
}
__device__ __forceinline__ unsigned short f2h(float f){
  return __builtin_bit_cast(unsigned short, (_Float16)f);
}
__device__ __forceinline__ float h2f(unsigned short u){
  return (float)__builtin_bit_cast(_Float16, u);
}
__device__ __forceinline__ f32x4 mfma16(f16x8 a, f16x8 b, f32x4 c){
  return __builtin_amdgcn_mfma_f32_16x16x32_f16(a, b, c, 0, 0, 0);
}

// A-fragment from an LDS [32][128] f16 tile.
__device__ __forceinline__ f16x8 ldsA(const unsigned short* buf, int rb, int s, int lane){
  return *(const f16x8*)(buf + (rb*16 + (lane&15))*128 + s*32 + ((lane>>4)<<3));
}

// ---------- PREP: all 5 weight transposes + k1 hidden, one launch ----------
__global__ __launch_bounds__(256) void prep_kernel(
    const float* __restrict__ obs, const float* __restrict__ hw1,
    const float* __restrict__ hb1, const float* __restrict__ hw2,
    const float* __restrict__ vw1, const float* __restrict__ vw2,
    const float* __restrict__ aw1, const float* __restrict__ aw2,
    unsigned short* __restrict__ wt2, unsigned short* __restrict__ vw1t,
    unsigned short* __restrict__ vw2t, unsigned short* __restrict__ aw1t,
    unsigned short* __restrict__ aw2t, unsigned short* __restrict__ h16){
  int b = blockIdx.x, t = threadIdx.x;
  if (b < 1616){
    __shared__ float tile[32][33];
    const float* in; unsigned short* out; int R, C, bx, by;
    if (b < 1536)      { in=hw2; out=wt2;  R=128; C=12288; bx=b%384;      by=b/384; }
    else if (b < 1552) { int q=b-1536; in=vw1; out=vw1t; R=128; C=128; bx=q&3; by=q>>2; }
    else if (b < 1568) { int q=b-1552; in=vw2; out=vw2t; R=128; C=128; bx=q&3; by=q>>2; }
    else if (b < 1600) { int q=b-1568; in=aw1; out=aw1t; R=256; C=128; bx=q&3; by=q>>2; }
    else               { int q=b-1600; in=aw2; out=aw2t; R=128; C=128; bx=q&3; by=q>>2; }
    int c0=bx*32, r0=by*32, tx=t&31, ty=t>>5;
    #pragma unroll
    for (int j=ty; j<32; j+=8) tile[j][tx] = in[(size_t)(r0+j)*C + c0 + tx];
    __syncthreads();
    #pragma unroll
    for (int j=ty; j<32; j+=8) out[(size_t)(c0+j)*R + r0 + tx] = f2h(tile[tx][j]);
  } else {
    __shared__ float w_s[96*128];
    __shared__ float x_s[32*96];
    __shared__ float b_s[128];
    int n0 = (b-1616)*32;
    for (int idx=t; idx<96*128; idx+=256) w_s[idx] = hw1[idx];
    if (t < 128) b_s[t] = hb1[t];
    for (int idx=t; idx<32*96; idx+=256){
      int r = idx/96, i = idx - r*96;
      int n = n0 + r; int bb = n>>3, l = n&7;
      x_s[idx] = (i<64) ? obs[bb*360 + i] : obs[bb*360 + 104 + (l<<5) + (i-64)];
    }
    __syncthreads();
    for (int e=t; e<32*128; e+=256){
      int r = e>>7, o = e&127;
      float acc = b_s[o];
      const float* xr = &x_s[r*96];
      #pragma unroll 4
      for (int i=0;i<96;++i) acc = fmaf(xr[i], w_s[i*128+o], acc);
      h16[(size_t)(n0+r)*128 + o] = f2h(tanh_fast(acc));
    }
  }
}

// ---------- K2: fused hypernet GEMM + tanh + x-contraction ----------
// grid 512: blockIdx = rowTile*4 + iQuarter. 64 rows/block, i in [iq*24, +24).
// 8 waves own 16 output cols each for all 4 row-blocks. 2 blocks/CU (4 waves/SIMD).
// Register budget (fits 128 arch VGPRs): af[4][4]=64, B dbuf=32, facc=16, addr ~14.
__global__ __launch_bounds__(512, 4) void k2_hyper(const float* __restrict__ obs,
    const unsigned short* __restrict__ h16, const unsigned short* __restrict__ wt2,
    const float* __restrict__ hb2, float* __restrict__ accg){
  __shared__ float x_s[24*64];   // [i_local][row]
  int t = threadIdx.x, lane = t & 63, w = t >> 6;
  int rt = blockIdx.x >> 2, iq = blockIdx.x & 3;
  int R0 = rt*64, ibase = iq*24;
  int wcol = w*16 + (lane&15);
  int kof  = (lane>>4) << 3;
  int rloc = (lane>>4) << 2;

  for (int idx=t; idx<24*64; idx+=512){
    int il = idx>>6, r = idx&63;
    int i = ibase + il;
    int n = R0 + r; int bb = n>>3, l = n&7;
    x_s[idx] = (i<64) ? obs[bb*360 + i] : obs[bb*360 + 104 + (l<<5) + (i-64)];
  }

  // A fragments for 4 row-blocks of 16 rows (i-invariant, held in registers)
  f16x8 af[4][4];
  #pragma unroll
  for (int rb=0; rb<4; ++rb)
    #pragma unroll
    for (int s=0; s<4; ++s)
      af[rb][s] = *(const f16x8*)(h16 + (size_t)(R0 + rb*16 + (lane&15))*128 + s*32 + kof);

  __syncthreads();

  float facc[4][4];
  #pragma unroll
  for (int rb=0;rb<4;++rb)
    #pragma unroll
    for (int reg=0;reg<4;++reg) facc[rb][reg] = 0.f;

  const unsigned short* wp = wt2 + (size_t)(ibase*128 + wcol)*128 + kof;
  const float* bp = hb2 + ibase*128 + wcol;

  f16x8 A0,A1,A2,A3, B0,B1,B2,B3;
  float biasA, biasB;

#define K2L(X0,X1,X2,X3,BI) do{                 \
    X0 = *(const f16x8*)(wp);                   \
    X1 = *(const f16x8*)(wp+32);                \
    X2 = *(const f16x8*)(wp+64);                \
    X3 = *(const f16x8*)(wp+96);                \
    BI = *bp;                                   \
    wp += 16384; bp += 128;                     \
  }while(0)

#define K2C(X0,X1,X2,X3,BI,IL) do{                                       \
    _Pragma("unroll")                                                    \
    for (int rb=0; rb<4; rb+=2){                                         \
      f32x4 a0 = {BI,BI,BI,BI}, a1 = {BI,BI,BI,BI};                      \
      a0 = mfma16(af[rb][0], X0, a0); a1 = mfma16(af[rb+1][0], X0, a1);  \
      a0 = mfma16(af[rb][1], X1, a0); a1 = mfma16(af[rb+1][1], X1, a1);  \
      a0 = mfma16(af[rb][2], X2, a0); a1 = mfma16(af[rb+1][2], X2, a1);  \
      a0 = mfma16(af[rb][3], X3, a0); a1 = mfma16(af[rb+1][3], X3, a1);  \
      f32x4 x0 = *(const f32x4*)(x_s + (IL)*64 + rb*16 + rloc);          \
      f32x4 x1 = *(const f32x4*)(x_s + (IL)*64 + (rb+1)*16 + rloc);      \
      _Pragma("unroll")                                                  \
      for (int reg=0; reg<4; ++reg){                                     \
        facc[rb][reg]   = fmaf(x0[reg], tanh_fast(a0[reg]), facc[rb][reg]);   \
        facc[rb+1][reg] = fmaf(x1[reg], tanh_fast(a1[reg]), facc[rb+1][reg]); \
      }                                                                  \
    }                                                                    \
  }while(0)

  K2L(A0,A1,A2,A3,biasA);
  K2L(B0,B1,B2,B3,biasB);
  for (int il=0; il<22; il+=2){
    K2C(A0,A1,A2,A3,biasA,il);
    K2L(A0,A1,A2,A3,biasA);
    K2C(B0,B1,B2,B3,biasB,il+1);
    K2L(B0,B1,B2,B3,biasB);
  }
  K2C(A0,A1,A2,A3,biasA,22);
  K2C(B0,B1,B2,B3,biasB,23);
#undef K2L
#undef K2C

  #pragma unroll
  for (int rb=0; rb<4; ++rb)
    #pragma unroll
    for (int reg=0; reg<4; ++reg)
      atomicAdd(&accg[(size_t)(R0 + rb*16 + rloc + reg)*128 + wcol], facc[rb][reg]);
}

// ---------- K3: per-batch landmark mean of tanh(accg) -> mean16 ----------
__global__ __launch_bounds__(256) void k3_mean(const float* __restrict__ accg,
    unsigned short* __restrict__ mean16){
  int t = threadIdx.x, B0 = blockIdx.x*4;
  for (int task=t; task<512; task+=256){
    int bl = task>>7, o = task&127;
    float m = 0.f;
    #pragma unroll
    for (int l=0;l<8;++l)
      m += tanh_fast(accg[(size_t)((B0 + bl)*8 + l)*128 + o]);
    mean16[(size_t)(B0 + bl)*128 + o] = f2h(m * 0.125f);
  }
}

// ---------- K4: emb from accg + fused MLP chain + softmax + final ----------
template<int KS>
__device__ __forceinline__ void stage(const unsigned short* inA, const unsigned short* inB,
    const unsigned short* wt, const float* bias, unsigned short* outb, int w, int lane){
  #pragma unroll
  for (int obl=0; obl<2; ++obl){
    int col = ((w*2+obl)<<4) + (lane&15);
    f32x4 a0 = {0.f,0.f,0.f,0.f}, a1v = {0.f,0.f,0.f,0.f};
    #pragma unroll
    for (int s=0;s<KS;++s){
      f16x8 bfr = *(const f16x8*)(wt + (size_t)col*(KS*32) + s*32 + ((lane>>4)<<3));
      f16x8 aa0, aa1;
      if (KS==8 && s>=4){ aa0 = ldsA(inB,0,s-4,lane); aa1 = ldsA(inB,1,s-4,lane); }
      else              { aa0 = ldsA(inA,0,s,lane);   aa1 = ldsA(inA,1,s,lane);   }
      a0  = mfma16(aa0, bfr, a0);
      a1v = mfma16(aa1, bfr, a1v);
    }
    float bb = bias[col];
    #pragma unroll
    for (int reg=0;reg<4;++reg){
      int r0 = ((lane>>4)<<2) + reg;
      outb[r0*128 + col]      = f2h(tanh_fast(a0[reg] + bb));
      outb[(16+r0)*128 + col] = f2h(tanh_fast(a1v[reg] + bb));
    }
  }
}

__global__ __launch_bounds__(256) void k4_mlp(
    const float* __restrict__ accg, const unsigned short* __restrict__ mean16,
    const unsigned short* __restrict__ vw1t, const unsigned short* __restrict__ vw2t,
    const unsigned short* __restrict__ aw1t, const unsigned short* __restrict__ aw2t,
    const float* __restrict__ vb1, const float* __restrict__ vb2,
    const float* __restrict__ ab1, const float* __restrict__ ab2,
    const float* __restrict__ aw3, const float* __restrict__ ab3,
    float* __restrict__ outp){
  __shared__ unsigned short bufE[32*128];
  __shared__ unsigned short bufM[32*128];
  __shared__ unsigned short bufA[32*128];
  __shared__ float fin[4*128];
  __shared__ float lp[32*8];
  __shared__ float att_s[32];
  int t = threadIdx.x, lane = t&63, w = t>>6;
  int R0 = blockIdx.x*32;

  // emb = tanh(accg) for our 32 rows
  for (int idx=t; idx<4096; idx+=256)
    bufE[idx] = f2h(tanh_fast(accg[(size_t)R0*128 + idx]));
  // mean_rep faithful ordering: row n pairs with mean[(n % 1024)]
  for (int idx=t; idx<512; idx+=256){
    int r = idx>>4, c8 = (idx&15)<<3;
    int n = R0 + r;
    *(uint4*)(bufM + r*128 + c8) = *(const uint4*)(mean16 + (size_t)(n & 1023)*128 + c8);
  }
  for (int idx=t; idx<512; idx+=256) fin[idx] = 0.f;
  __syncthreads();

  stage<8>(bufE, bufM, aw1t, ab1, bufA, w, lane);
  __syncthreads();
  stage<4>(bufA, nullptr, aw2t, ab2, bufM, w, lane);
  __syncthreads();
  {
    int r = t>>3, seg = t&7;
    float p = 0.f;
    const unsigned short* row = bufM + r*128 + seg*16;
    const float* w3 = aw3 + seg*16;
    #pragma unroll
    for (int k=0;k<16;++k) p += h2f(row[k]) * w3[k];
    lp[r*8+seg] = p;
  }
  __syncthreads();
  if (t < 4){
    float lg[8]; float mx = -1e30f;
    for (int l=0;l<8;++l){
      float s = ab3[0];
      #pragma unroll
      for (int sg=0;sg<8;++sg) s += lp[(t*8+l)*8+sg];
      lg[l] = s; mx = fmaxf(mx, s);
    }
    float sum = 0.f;
    for (int l=0;l<8;++l){ lg[l] = __builtin_amdgcn_exp2f((lg[l]-mx)*1.44269504089f); sum += lg[l]; }
    float inv = __builtin_amdgcn_rcpf(sum);
    for (int l=0;l<8;++l) att_s[t*8+l] = lg[l]*inv;
  }
  __syncthreads();
  stage<4>(bufE, nullptr, vw1t, vb1, bufA, w, lane);
  __syncthreads();
  {
    #pragma unroll
    for (int obl=0; obl<2; ++obl){
      int col = ((w*2+obl)<<4) + (lane&15);
      f32x4 a0 = {0.f,0.f,0.f,0.f}, a1v = {0.f,0.f,0.f,0.f};
      #pragma unroll
      for (int s=0;s<4;++s){
        f16x8 bfr = *(const f16x8*)(vw2t + (size_t)col*128 + s*32 + ((lane>>4)<<3));
        a0  = mfma16(ldsA(bufA,0,s,lane), bfr, a0);
        a1v = mfma16(ldsA(bufA,1,s,lane), bfr, a1v);
      }
      float bb = vb2[col];
      #pragma unroll
      for (int reg=0;reg<4;++reg){
        int r0 = ((lane>>4)<<2) + reg;
        float v0 = tanh_fast(a0[reg]+bb);
        float v1 = tanh_fast(a1v[reg]+bb);
        atomicAdd(&fin[((r0)>>3)*128 + col],    att_s[r0]    * v0);
        atomicAdd(&fin[((16+r0)>>3)*128 + col], att_s[16+r0] * v1);
      }
    }
  }
  __syncthreads();
  for (int idx=t; idx<512; idx+=256){
    int b_loc = idx>>7, o = idx&127;
    outp[(size_t)(R0/8 + b_loc)*128 + o] = fin[idx];
  }
}

// ---------- launch ----------
extern "C" void kernel_launch(void* const* d_in, const int* in_sizes, int n_in,
                              void* d_out, int out_size, void* d_ws, size_t ws_size,
                              hipStream_t stream){
  const float* obs = (const float*)d_in[0];
  const float* hw1 = (const float*)d_in[3];
  const float* hb1 = (const float*)d_in[4];
  const float* hw2 = (const float*)d_in[5];
  const float* hb2 = (const float*)d_in[6];
  const float* vw1 = (const float*)d_in[7];
  const float* vb1 = (const float*)d_in[8];
  const float* vw2 = (const float*)d_in[9];
  const float* vb2 = (const float*)d_in[10];
  const float* aw1 = (const float*)d_in[11];
  const float* ab1 = (const float*)d_in[12];
  const float* aw2 = (const float*)d_in[13];
  const float* ab2 = (const float*)d_in[14];
  const float* aw3 = (const float*)d_in[15];
  const float* ab3 = (const float*)d_in[16];

  char* ws = (char*)d_ws;
  unsigned short* wt2    = (unsigned short*)(ws);             // 3,145,728 B
  unsigned short* mean16 = (unsigned short*)(ws);             //   262,144 B (alias; wt2 dead after k2)
  unsigned short* h16    = (unsigned short*)(ws + 3145728);   // 2,097,152 B
  float*          accg   = (float*)        (ws + 5242880);    // 4,194,304 B
  unsigned short* vw1t   = (unsigned short*)(ws + 9437184);   //    32,768 B
  unsigned short* vw2t   = (unsigned short*)(ws + 9469952);   //    32,768 B
  unsigned short* aw1t   = (unsigned short*)(ws + 9502720);   //    65,536 B
  unsigned short* aw2t   = (unsigned short*)(ws + 9568256);   //    32,768 B  (end 9,601,024)
  float* outp = (float*)d_out;

  hipMemsetAsync(accg, 0, 8192*128*sizeof(float), stream);
  prep_kernel<<<1872, 256, 0, stream>>>(obs, hw1, hb1, hw2, vw1, vw2, aw1, aw2,
                                        wt2, vw1t, vw2t, aw1t, aw2t, h16);
  k2_hyper<<<512, 512, 0, stream>>>(obs, h16, wt2, hb2, accg);
  k3_mean<<<256, 256, 0, stream>>>(accg, mean16);
  k4_mlp<<<256, 256, 0, stream>>>(accg, mean16, vw1t, vw2t, aw1t, aw2t,
                                  vb1, vb2, ab1, ab2, aw3, ab3, outp);
}

// Round 8
// 154.065 us; speedup vs baseline: 1.0691x; 1.0691x over previous
//
#include <hip/hip_runtime.h>

// ---------- types / helpers ----------
typedef _Float16 f16x8 __attribute__((ext_vector_type(8)));
typedef float f32x4 __attribute__((ext_vector_type(4)));

__device__ __forceinline__ float tanh_fast(float x){
  // tanh(x) = 1 - 2/(1+exp2(2*log2e*x)); exact at saturation
  float e = __builtin_amdgcn_exp2f(x * 2.88539008177793f);
  return 1.f - 2.f * __builtin_amdgcn_rcpf(1.f + e);
}
__device__ __forceinline__ unsigned short f2h(float f){
  return __builtin_bit_cast(unsigned short, (_Float16)f);
}
__device__ __forceinline__ float h2f(unsigned short u){
  return (float)__builtin_bit_cast(_Float16, u);
}
__device__ __forceinline__ f32x4 mfma16(f16x8 a, f16x8 b, f32x4 c){
  return __builtin_amdgcn_mfma_f32_16x16x32_f16(a, b, c, 0, 0, 0);
}

// A-fragment from an LDS [32][128] f16 tile.
__device__ __forceinline__ f16x8 ldsA(const unsigned short* buf, int rb, int s, int lane){
  return *(const f16x8*)(buf + (rb*16 + (lane&15))*128 + s*32 + ((lane>>4)<<3));
}

// ---------- PREP: all 5 weight transposes + k1 hidden, one launch ----------
__global__ __launch_bounds__(256) void prep_kernel(
    const float* __restrict__ obs, const float* __restrict__ hw1,
    const float* __restrict__ hb1, const float* __restrict__ hw2,
    const float* __restrict__ vw1, const float* __restrict__ vw2,
    const float* __restrict__ aw1, const float* __restrict__ aw2,
    unsigned short* __restrict__ wt2, unsigned short* __restrict__ vw1t,
    unsigned short* __restrict__ vw2t, unsigned short* __restrict__ aw1t,
    unsigned short* __restrict__ aw2t, unsigned short* __restrict__ h16){
  int b = blockIdx.x, t = threadIdx.x;
  if (b < 1616){
    __shared__ float tile[32][33];
    const float* in; unsigned short* out; int R, C, bx, by;
    if (b < 1536)      { in=hw2; out=wt2;  R=128; C=12288; bx=b%384;      by=b/384; }
    else if (b < 1552) { int q=b-1536; in=vw1; out=vw1t; R=128; C=128; bx=q&3; by=q>>2; }
    else if (b < 1568) { int q=b-1552; in=vw2; out=vw2t; R=128; C=128; bx=q&3; by=q>>2; }
    else if (b < 1600) { int q=b-1568; in=aw1; out=aw1t; R=256; C=128; bx=q&3; by=q>>2; }
    else               { int q=b-1600; in=aw2; out=aw2t; R=128; C=128; bx=q&3; by=q>>2; }
    int c0=bx*32, r0=by*32, tx=t&31, ty=t>>5;
    #pragma unroll
    for (int j=ty; j<32; j+=8) tile[j][tx] = in[(size_t)(r0+j)*C + c0 + tx];
    __syncthreads();
    #pragma unroll
    for (int j=ty; j<32; j+=8) out[(size_t)(c0+j)*R + r0 + tx] = f2h(tile[tx][j]);
  } else {
    __shared__ float w_s[96*128];
    __shared__ float x_s[32*96];
    __shared__ float b_s[128];
    int n0 = (b-1616)*32;
    for (int idx=t; idx<96*128; idx+=256) w_s[idx] = hw1[idx];
    if (t < 128) b_s[t] = hb1[t];
    for (int idx=t; idx<32*96; idx+=256){
      int r = idx/96, i = idx - r*96;
      int n = n0 + r; int bb = n>>3, l = n&7;
      x_s[idx] = (i<64) ? obs[bb*360 + i] : obs[bb*360 + 104 + (l<<5) + (i-64)];
    }
    __syncthreads();
    for (int e=t; e<32*128; e+=256){
      int r = e>>7, o = e&127;
      float acc = b_s[o];
      const float* xr = &x_s[r*96];
      #pragma unroll 4
      for (int i=0;i<96;++i) acc = fmaf(xr[i], w_s[i*128+o], acc);
      h16[(size_t)(n0+r)*128 + o] = f2h(tanh_fast(acc));
    }
  }
}

// ---------- K2: fused hypernet GEMM + tanh + x-contraction ----------
// grid 512: blockIdx = rt*2 + ih. 32 rows/block, i in [ih*48, +48).
// 8 waves own 16 output cols each for 2 row-blocks. NO atomics: block (rt,ih)
// plain-stores its partial sums to accg[ih]; k3/k4 sum the two halves.
// amdgpu_waves_per_eu(4,4) pins allocation at 4 waves/EU (<=128 VGPR, need ~95).
__global__ __launch_bounds__(512) __attribute__((amdgpu_waves_per_eu(4,4)))
void k2_hyper(const float* __restrict__ obs,
    const unsigned short* __restrict__ h16, const unsigned short* __restrict__ wt2,
    const float* __restrict__ hb2, float* __restrict__ accg_base){
  __shared__ float x_s[48*32];   // [i_local][row]
  int t = threadIdx.x, lane = t & 63, w = t >> 6;
  int rt = blockIdx.x >> 1, ih = blockIdx.x & 1;
  int R0 = rt*32, ibase = ih*48;
  float* accg = accg_base + (size_t)ih*8192*128;
  int wcol = w*16 + (lane&15);
  int kof  = (lane>>4) << 3;
  int rloc = (lane>>4) << 2;

  for (int idx=t; idx<48*32; idx+=512){
    int il = idx>>5, r = idx&31;
    int i = ibase + il;
    int n = R0 + r; int bb = n>>3, l = n&7;
    x_s[idx] = (i<64) ? obs[bb*360 + i] : obs[bb*360 + 104 + (l<<5) + (i-64)];
  }

  // A fragments for 2 row-blocks of 16 rows (i-invariant, held in registers)
  f16x8 af[2][4];
  #pragma unroll
  for (int rb=0; rb<2; ++rb)
    #pragma unroll
    for (int s=0; s<4; ++s)
      af[rb][s] = *(const f16x8*)(h16 + (size_t)(R0 + rb*16 + (lane&15))*128 + s*32 + kof);

  __syncthreads();

  float facc[2][4];
  #pragma unroll
  for (int rb=0;rb<2;++rb)
    #pragma unroll
    for (int reg=0;reg<4;++reg) facc[rb][reg] = 0.f;

  const unsigned short* wp = wt2 + (size_t)(ibase*128 + wcol)*128 + kof;
  const float* bp = hb2 + ibase*128 + wcol;

  f16x8 A0,A1,A2,A3, B0,B1,B2,B3;
  float biasA, biasB;

#define K2L(X0,X1,X2,X3,BI) do{                 \
    X0 = *(const f16x8*)(wp);                   \
    X1 = *(const f16x8*)(wp+32);                \
    X2 = *(const f16x8*)(wp+64);                \
    X3 = *(const f16x8*)(wp+96);                \
    BI = *bp;                                   \
    wp += 16384; bp += 128;                     \
  }while(0)

#define K2C(X0,X1,X2,X3,BI,IL) do{                                       \
    f32x4 a0 = {BI,BI,BI,BI}, a1 = {BI,BI,BI,BI};                        \
    a0 = mfma16(af[0][0], X0, a0); a1 = mfma16(af[1][0], X0, a1);        \
    a0 = mfma16(af[0][1], X1, a0); a1 = mfma16(af[1][1], X1, a1);        \
    a0 = mfma16(af[0][2], X2, a0); a1 = mfma16(af[1][2], X2, a1);        \
    a0 = mfma16(af[0][3], X3, a0); a1 = mfma16(af[1][3], X3, a1);        \
    f32x4 x0 = *(const f32x4*)(x_s + (IL)*32 + rloc);                    \
    f32x4 x1 = *(const f32x4*)(x_s + (IL)*32 + 16 + rloc);               \
    _Pragma("unroll")                                                    \
    for (int reg=0; reg<4; ++reg){                                       \
      facc[0][reg] = fmaf(x0[reg], tanh_fast(a0[reg]), facc[0][reg]);    \
      facc[1][reg] = fmaf(x1[reg], tanh_fast(a1[reg]), facc[1][reg]);    \
    }                                                                    \
  }while(0)

  K2L(A0,A1,A2,A3,biasA);
  K2L(B0,B1,B2,B3,biasB);
  for (int il=0; il<46; il+=2){
    K2C(A0,A1,A2,A3,biasA,il);
    K2L(A0,A1,A2,A3,biasA);
    K2C(B0,B1,B2,B3,biasB,il+1);
    K2L(B0,B1,B2,B3,biasB);
  }
  K2C(A0,A1,A2,A3,biasA,46);
  K2C(B0,B1,B2,B3,biasB,47);
#undef K2L
#undef K2C

  // plain stores: each (row,col) of this half owned by exactly one lane
  #pragma unroll
  for (int rb=0; rb<2; ++rb)
    #pragma unroll
    for (int reg=0; reg<4; ++reg)
      accg[(size_t)(R0 + rb*16 + rloc + reg)*128 + wcol] = facc[rb][reg];
}

// ---------- K3: per-batch landmark mean of tanh(accgA+accgB) -> mean16 ----------
__global__ __launch_bounds__(256) void k3_mean(const float* __restrict__ accgA,
    unsigned short* __restrict__ mean16){
  const float* accgB = accgA + (size_t)8192*128;
  int t = threadIdx.x, B0 = blockIdx.x*4;
  for (int task=t; task<512; task+=256){
    int bl = task>>7, o = task&127;
    float m = 0.f;
    #pragma unroll
    for (int l=0;l<8;++l){
      size_t cell = (size_t)((B0 + bl)*8 + l)*128 + o;
      m += tanh_fast(accgA[cell] + accgB[cell]);
    }
    mean16[(size_t)(B0 + bl)*128 + o] = f2h(m * 0.125f);
  }
}

// ---------- K4: emb from accg halves + fused MLP chain + softmax + final ----------
template<int KS>
__device__ __forceinline__ void stage(const unsigned short* inA, const unsigned short* inB,
    const unsigned short* wt, const float* bias, unsigned short* outb, int w, int lane){
  #pragma unroll
  for (int obl=0; obl<2; ++obl){
    int col = ((w*2+obl)<<4) + (lane&15);
    f32x4 a0 = {0.f,0.f,0.f,0.f}, a1v = {0.f,0.f,0.f,0.f};
    #pragma unroll
    for (int s=0;s<KS;++s){
      f16x8 bfr = *(const f16x8*)(wt + (size_t)col*(KS*32) + s*32 + ((lane>>4)<<3));
      f16x8 aa0, aa1;
      if (KS==8 && s>=4){ aa0 = ldsA(inB,0,s-4,lane); aa1 = ldsA(inB,1,s-4,lane); }
      else              { aa0 = ldsA(inA,0,s,lane);   aa1 = ldsA(inA,1,s,lane);   }
      a0  = mfma16(aa0, bfr, a0);
      a1v = mfma16(aa1, bfr, a1v);
    }
    float bb = bias[col];
    #pragma unroll
    for (int reg=0;reg<4;++reg){
      int r0 = ((lane>>4)<<2) + reg;
      outb[r0*128 + col]      = f2h(tanh_fast(a0[reg] + bb));
      outb[(16+r0)*128 + col] = f2h(tanh_fast(a1v[reg] + bb));
    }
  }
}

__global__ __launch_bounds__(256) void k4_mlp(
    const float* __restrict__ accgA, const unsigned short* __restrict__ mean16,
    const unsigned short* __restrict__ vw1t, const unsigned short* __restrict__ vw2t,
    const unsigned short* __restrict__ aw1t, const unsigned short* __restrict__ aw2t,
    const float* __restrict__ vb1, const float* __restrict__ vb2,
    const float* __restrict__ ab1, const float* __restrict__ ab2,
    const float* __restrict__ aw3, const float* __restrict__ ab3,
    float* __restrict__ outp){
  const float* accgB = accgA + (size_t)8192*128;
  __shared__ unsigned short bufE[32*128];
  __shared__ unsigned short bufM[32*128];
  __shared__ unsigned short bufA[32*128];
  __shared__ float fin[4*128];
  __shared__ float lp[32*8];
  __shared__ float att_s[32];
  int t = threadIdx.x, lane = t&63, w = t>>6;
  int R0 = blockIdx.x*32;

  // emb = tanh(accgA+accgB) for our 32 rows
  for (int idx=t; idx<4096; idx+=256){
    size_t cell = (size_t)R0*128 + idx;
    bufE[idx] = f2h(tanh_fast(accgA[cell] + accgB[cell]));
  }
  // mean_rep faithful ordering: row n pairs with mean[(n % 1024)]
  for (int idx=t; idx<512; idx+=256){
    int r = idx>>4, c8 = (idx&15)<<3;
    int n = R0 + r;
    *(uint4*)(bufM + r*128 + c8) = *(const uint4*)(mean16 + (size_t)(n & 1023)*128 + c8);
  }
  for (int idx=t; idx<512; idx+=256) fin[idx] = 0.f;
  __syncthreads();

  stage<8>(bufE, bufM, aw1t, ab1, bufA, w, lane);
  __syncthreads();
  stage<4>(bufA, nullptr, aw2t, ab2, bufM, w, lane);
  __syncthreads();
  {
    int r = t>>3, seg = t&7;
    float p = 0.f;
    const unsigned short* row = bufM + r*128 + seg*16;
    const float* w3 = aw3 + seg*16;
    #pragma unroll
    for (int k=0;k<16;++k) p += h2f(row[k]) * w3[k];
    lp[r*8+seg] = p;
  }
  __syncthreads();
  if (t < 4){
    float lg[8]; float mx = -1e30f;
    for (int l=0;l<8;++l){
      float s = ab3[0];
      #pragma unroll
      for (int sg=0;sg<8;++sg) s += lp[(t*8+l)*8+sg];
      lg[l] = s; mx = fmaxf(mx, s);
    }
    float sum = 0.f;
    for (int l=0;l<8;++l){ lg[l] = __builtin_amdgcn_exp2f((lg[l]-mx)*1.44269504089f); sum += lg[l]; }
    float inv = __builtin_amdgcn_rcpf(sum);
    for (int l=0;l<8;++l) att_s[t*8+l] = lg[l]*inv;
  }
  __syncthreads();
  stage<4>(bufE, nullptr, vw1t, vb1, bufA, w, lane);
  __syncthreads();
  {
    #pragma unroll
    for (int obl=0; obl<2; ++obl){
      int col = ((w*2+obl)<<4) + (lane&15);
      f32x4 a0 = {0.f,0.f,0.f,0.f}, a1v = {0.f,0.f,0.f,0.f};
      #pragma unroll
      for (int s=0;s<4;++s){
        f16x8 bfr = *(const f16x8*)(vw2t + (size_t)col*128 + s*32 + ((lane>>4)<<3));
        a0  = mfma16(ldsA(bufA,0,s,lane), bfr, a0);
        a1v = mfma16(ldsA(bufA,1,s,lane), bfr, a1v);
      }
      float bb = vb2[col];
      #pragma unroll
      for (int reg=0;reg<4;++reg){
        int r0 = ((lane>>4)<<2) + reg;
        float v0 = tanh_fast(a0[reg]+bb);
        float v1 = tanh_fast(a1v[reg]+bb);
        atomicAdd(&fin[((r0)>>3)*128 + col],    att_s[r0]    * v0);
        atomicAdd(&fin[((16+r0)>>3)*128 + col], att_s[16+r0] * v1);
      }
    }
  }
  __syncthreads();
  for (int idx=t; idx<512; idx+=256){
    int b_loc = idx>>7, o = idx&127;
    outp[(size_t)(R0/8 + b_loc)*128 + o] = fin[idx];
  }
}

// ---------- launch ----------
extern "C" void kernel_launch(void* const* d_in, const int* in_sizes, int n_in,
                              void* d_out, int out_size, void* d_ws, size_t ws_size,
                              hipStream_t stream){
  const float* obs = (const float*)d_in[0];
  const float* hw1 = (const float*)d_in[3];
  const float* hb1 = (const float*)d_in[4];
  const float* hw2 = (const float*)d_in[5];
  const float* hb2 = (const float*)d_in[6];
  const float* vw1 = (const float*)d_in[7];
  const float* vb1 = (const float*)d_in[8];
  const float* vw2 = (const float*)d_in[9];
  const float* vb2 = (const float*)d_in[10];
  const float* aw1 = (const float*)d_in[11];
  const float* ab1 = (const float*)d_in[12];
  const float* aw2 = (const float*)d_in[13];
  const float* ab2 = (const float*)d_in[14];
  const float* aw3 = (const float*)d_in[15];
  const float* ab3 = (const float*)d_in[16];

  char* ws = (char*)d_ws;
  unsigned short* wt2    = (unsigned short*)(ws);             // 3,145,728 B
  unsigned short* mean16 = (unsigned short*)(ws);             //   262,144 B (alias; wt2 dead after k2)
  unsigned short* h16    = (unsigned short*)(ws + 3145728);   // 2,097,152 B
  float*          accg   = (float*)        (ws + 5242880);    // 2 x 4,194,304 B (split-K halves)
  unsigned short* vw1t   = (unsigned short*)(ws + 13631488);  //    32,768 B
  unsigned short* vw2t   = (unsigned short*)(ws + 13664256);  //    32,768 B
  unsigned short* aw1t   = (unsigned short*)(ws + 13697024);  //    65,536 B
  unsigned short* aw2t   = (unsigned short*)(ws + 13762560);  //    32,768 B  (end 13,795,328)
  float* outp = (float*)d_out;

  prep_kernel<<<1872, 256, 0, stream>>>(obs, hw1, hb1, hw2, vw1, vw2, aw1, aw2,
                                        wt2, vw1t, vw2t, aw1t, aw2t, h16);
  k2_hyper<<<512, 512, 0, stream>>>(obs, h16, wt2, hb2, accg);
  k3_mean<<<256, 256, 0, stream>>>(accg, mean16);
  k4_mlp<<<256, 256, 0, stream>>>(accg, mean16, vw1t, vw2t, aw1t, aw2t,
                                  vb1, vb2, ab1, ab2, aw3, ab3, outp);
}

// Round 9
// 121.167 us; speedup vs baseline: 1.3594x; 1.2715x over previous
//
#include <hip/hip_runtime.h>

// ---------- types / helpers ----------
typedef _Float16 f16x8 __attribute__((ext_vector_type(8)));
typedef float f32x4 __attribute__((ext_vector_type(4)));
typedef const __attribute__((address_space(1))) void* as1_cvp;
typedef __attribute__((address_space(3))) void* as3_vp;

__device__ __forceinline__ float tanh_fast(float x){
  // tanh(x) = 1 - 2/(1+exp2(2*log2e*x)); exact at saturation
  float e = __builtin_amdgcn_exp2f(x * 2.88539008177793f);
  return 1.f - 2.f * __builtin_amdgcn_rcpf(1.f + e);
}
__device__ __forceinline__ unsigned short f2h(float f){
  return __builtin_bit_cast(unsigned short, (_Float16)f);
}
__device__ __forceinline__ float h2f(unsigned short u){
  return (float)__builtin_bit_cast(_Float16, u);
}
__device__ __forceinline__ f32x4 mfma16(f16x8 a, f16x8 b, f32x4 c){
  return __builtin_amdgcn_mfma_f32_16x16x32_f16(a, b, c, 0, 0, 0);
}

// A-fragment from an LDS [32][128] f16 tile.
__device__ __forceinline__ f16x8 ldsA(const unsigned short* buf, int rb, int s, int lane){
  return *(const f16x8*)(buf + (rb*16 + (lane&15))*128 + s*32 + ((lane>>4)<<3));
}

// ---------- PREP: all 5 weight transposes + k1 hidden, one launch ----------
// wt2 is written PRE-SWIZZLED: element (col,k) stored at [col>>7]*16384 + (col&127)*128
// + (k ^ ((col&7)<<3)) so k2's ds_read_b128 B-loads are bank-conflict-free.
__global__ __launch_bounds__(256) void prep_kernel(
    const float* __restrict__ obs, const float* __restrict__ hw1,
    const float* __restrict__ hb1, const float* __restrict__ hw2,
    const float* __restrict__ vw1, const float* __restrict__ vw2,
    const float* __restrict__ aw1, const float* __restrict__ aw2,
    unsigned short* __restrict__ wt2, unsigned short* __restrict__ vw1t,
    unsigned short* __restrict__ vw2t, unsigned short* __restrict__ aw1t,
    unsigned short* __restrict__ aw2t, unsigned short* __restrict__ h16){
  int b = blockIdx.x, t = threadIdx.x;
  if (b < 1616){
    __shared__ float tile[32][33];
    const float* in; unsigned short* out; int R, C, bx, by; bool swz;
    if (b < 1536)      { in=hw2; out=wt2;  R=128; C=12288; bx=b%384;      by=b/384; swz=true; }
    else if (b < 1552) { int q=b-1536; in=vw1; out=vw1t; R=128; C=128; bx=q&3; by=q>>2; swz=false; }
    else if (b < 1568) { int q=b-1552; in=vw2; out=vw2t; R=128; C=128; bx=q&3; by=q>>2; swz=false; }
    else if (b < 1600) { int q=b-1568; in=aw1; out=aw1t; R=256; C=128; bx=q&3; by=q>>2; swz=false; }
    else               { int q=b-1600; in=aw2; out=aw2t; R=128; C=128; bx=q&3; by=q>>2; swz=false; }
    int c0=bx*32, r0=by*32, tx=t&31, ty=t>>5;
    #pragma unroll
    for (int j=ty; j<32; j+=8) tile[j][tx] = in[(size_t)(r0+j)*C + c0 + tx];
    __syncthreads();
    if (swz){
      #pragma unroll
      for (int j=ty; j<32; j+=8){
        int col = c0+j, k = r0+tx;
        int ig = col>>7, colL = col&127;
        out[(size_t)ig*16384 + colL*128 + (k ^ ((colL&7)<<3))] = f2h(tile[tx][j]);
      }
    } else {
      #pragma unroll
      for (int j=ty; j<32; j+=8) out[(size_t)(c0+j)*R + r0 + tx] = f2h(tile[tx][j]);
    }
  } else {
    __shared__ float w_s[96*128];
    __shared__ float x_s[32*96];
    __shared__ float b_s[128];
    int n0 = (b-1616)*32;
    for (int idx=t; idx<96*128; idx+=256) w_s[idx] = hw1[idx];
    if (t < 128) b_s[t] = hb1[t];
    for (int idx=t; idx<32*96; idx+=256){
      int r = idx/96, i = idx - r*96;
      int n = n0 + r; int bb = n>>3, l = n&7;
      x_s[idx] = (i<64) ? obs[bb*360 + i] : obs[bb*360 + 104 + (l<<5) + (i-64)];
    }
    __syncthreads();
    for (int e=t; e<32*128; e+=256){
      int r = e>>7, o = e&127;
      float acc = b_s[o];
      const float* xr = &x_s[r*96];
      #pragma unroll 4
      for (int i=0;i<96;++i) acc = fmaf(xr[i], w_s[i*128+o], acc);
      h16[(size_t)(n0+r)*128 + o] = f2h(tanh_fast(acc));
    }
  }
}

// ---------- K2: LDS-staged hypernet GEMM + tanh + x-contraction ----------
// grid 256: blockIdx = rt*4 + iq. 128 rows/block, i in [iq*24, +24).
// Per i: 32KB wt2 tile -> LDS (global_load_lds, dbuf). 8 waves = 4 rowgrp x 2 colhalf.
// wt2 L2 traffic = 256 x 786KB = 201MB (was 805MB). Partial sums atomicAdd'ed (4-way).
__device__ __forceinline__ void stage_tile(const unsigned short* gsrc,
                                           unsigned short* lbuf, int t){
  const unsigned short* g = gsrc + t*8;
  unsigned short* l = lbuf + t*8;
  #pragma unroll
  for (int p=0;p<4;++p)
    __builtin_amdgcn_global_load_lds((as1_cvp)(g + p*4096), (as3_vp)(l + p*4096), 16, 0, 0);
}

__global__ __launch_bounds__(512, 2) void k2_hyper(const float* __restrict__ obs,
    const unsigned short* __restrict__ h16, const unsigned short* __restrict__ wt2,
    const float* __restrict__ hb2, float* __restrict__ accg){
  __shared__ unsigned short bts[2][16384];   // 2 x 32KB wt2 tiles
  __shared__ float x_s[24*128];              // [i_local][row]
  int t = threadIdx.x, lane = t & 63, w = t >> 6;
  int rt = blockIdx.x >> 2, iq = blockIdx.x & 3;
  int R0 = rt*128, ibase = iq*24;
  int rg = w & 3, cg = w >> 2;               // 4 row-groups x 2 col-halves
  int cl   = lane & 15;
  int kof  = (lane>>4) << 3;
  int rloc = (lane>>4) << 2;

  for (int idx=t; idx<24*128; idx+=512){
    int il = idx>>7, r = idx&127;
    int i = ibase + il;
    int n = R0 + r; int bb = n>>3, l = n&7;
    x_s[idx] = (i<64) ? obs[bb*360 + i] : obs[bb*360 + 104 + (l<<5) + (i-64)];
  }

  // A fragments: this wave's 32 rows (2 row-blocks), i-invariant
  f16x8 af[2][4];
  #pragma unroll
  for (int rb=0; rb<2; ++rb)
    #pragma unroll
    for (int s=0; s<4; ++s)
      af[rb][s] = *(const f16x8*)(h16 + (size_t)(R0 + rg*32 + rb*16 + cl)*128 + s*32 + kof);

  stage_tile(wt2 + (size_t)ibase*16384, bts[0], t);
  __syncthreads();   // drains vmcnt(0): tile 0 + x_s ready

  float facc[2][4][4];
  #pragma unroll
  for (int rb=0;rb<2;++rb)
    #pragma unroll
    for (int ch=0;ch<4;++ch)
      #pragma unroll
      for (int reg=0;reg<4;++reg) facc[rb][ch][reg] = 0.f;

  for (int it=0; it<24; ++it){
    const unsigned short* lb = bts[it&1];
    if (it < 23) stage_tile(wt2 + (size_t)(ibase+it+1)*16384, bts[(it+1)&1], t);
    const float* bias_p = hb2 + (ibase+it)*128;
    float xa[4], xb[4];
    #pragma unroll
    for (int reg=0;reg<4;++reg){
      xa[reg] = x_s[it*128 + rg*32 + rloc + reg];
      xb[reg] = x_s[it*128 + rg*32 + 16 + rloc + reg];
    }
    #pragma unroll
    for (int ch=0; ch<4; ++ch){
      int colL = cg*64 + ch*16 + cl;
      int sx = (colL&7)<<3;
      const unsigned short* bp = lb + colL*128;
      f16x8 b0 = *(const f16x8*)(bp + ((  0+kof)^sx));
      f16x8 b1 = *(const f16x8*)(bp + (( 32+kof)^sx));
      f16x8 b2 = *(const f16x8*)(bp + (( 64+kof)^sx));
      f16x8 b3 = *(const f16x8*)(bp + (( 96+kof)^sx));
      float bi = bias_p[colL];
      f32x4 a0 = {bi,bi,bi,bi}, a1 = {bi,bi,bi,bi};
      a0 = mfma16(af[0][0], b0, a0); a1 = mfma16(af[1][0], b0, a1);
      a0 = mfma16(af[0][1], b1, a0); a1 = mfma16(af[1][1], b1, a1);
      a0 = mfma16(af[0][2], b2, a0); a1 = mfma16(af[1][2], b2, a1);
      a0 = mfma16(af[0][3], b3, a0); a1 = mfma16(af[1][3], b3, a1);
      #pragma unroll
      for (int reg=0;reg<4;++reg){
        facc[0][ch][reg] = fmaf(xa[reg], tanh_fast(a0[reg]), facc[0][ch][reg]);
        facc[1][ch][reg] = fmaf(xb[reg], tanh_fast(a1[reg]), facc[1][ch][reg]);
      }
    }
    __syncthreads();   // compiler emits vmcnt(0) drain: next tile staged + all reads done
  }

  #pragma unroll
  for (int rb=0; rb<2; ++rb)
    #pragma unroll
    for (int ch=0; ch<4; ++ch)
      #pragma unroll
      for (int reg=0; reg<4; ++reg)
        atomicAdd(&accg[(size_t)(R0 + rg*32 + rb*16 + rloc + reg)*128 + cg*64 + ch*16 + cl],
                  facc[rb][ch][reg]);
}

// ---------- K3: per-batch landmark mean of tanh(accg) -> mean16 ----------
__global__ __launch_bounds__(256) void k3_mean(const float* __restrict__ accg,
    unsigned short* __restrict__ mean16){
  int t = threadIdx.x, B0 = blockIdx.x*4;
  for (int task=t; task<512; task+=256){
    int bl = task>>7, o = task&127;
    float m = 0.f;
    #pragma unroll
    for (int l=0;l<8;++l)
      m += tanh_fast(accg[(size_t)((B0 + bl)*8 + l)*128 + o]);
    mean16[(size_t)(B0 + bl)*128 + o] = f2h(m * 0.125f);
  }
}

// ---------- K4: emb from accg + fused MLP chain + softmax + final ----------
template<int KS>
__device__ __forceinline__ void stage(const unsigned short* inA, const unsigned short* inB,
    const unsigned short* wt, const float* bias, unsigned short* outb, int w, int lane){
  #pragma unroll
  for (int obl=0; obl<2; ++obl){
    int col = ((w*2+obl)<<4) + (lane&15);
    f32x4 a0 = {0.f,0.f,0.f,0.f}, a1v = {0.f,0.f,0.f,0.f};
    #pragma unroll
    for (int s=0;s<KS;++s){
      f16x8 bfr = *(const f16x8*)(wt + (size_t)col*(KS*32) + s*32 + ((lane>>4)<<3));
      f16x8 aa0, aa1;
      if (KS==8 && s>=4){ aa0 = ldsA(inB,0,s-4,lane); aa1 = ldsA(inB,1,s-4,lane); }
      else              { aa0 = ldsA(inA,0,s,lane);   aa1 = ldsA(inA,1,s,lane);   }
      a0  = mfma16(aa0, bfr, a0);
      a1v = mfma16(aa1, bfr, a1v);
    }
    float bb = bias[col];
    #pragma unroll
    for (int reg=0;reg<4;++reg){
      int r0 = ((lane>>4)<<2) + reg;
      outb[r0*128 + col]      = f2h(tanh_fast(a0[reg] + bb));
      outb[(16+r0)*128 + col] = f2h(tanh_fast(a1v[reg] + bb));
    }
  }
}

__global__ __launch_bounds__(256) void k4_mlp(
    const float* __restrict__ accg, const unsigned short* __restrict__ mean16,
    const unsigned short* __restrict__ vw1t, const unsigned short* __restrict__ vw2t,
    const unsigned short* __restrict__ aw1t, const unsigned short* __restrict__ aw2t,
    const float* __restrict__ vb1, const float* __restrict__ vb2,
    const float* __restrict__ ab1, const float* __restrict__ ab2,
    const float* __restrict__ aw3, const float* __restrict__ ab3,
    float* __restrict__ outp){
  __shared__ unsigned short bufE[32*128];
  __shared__ unsigned short bufM[32*128];
  __shared__ unsigned short bufA[32*128];
  __shared__ float fin[4*128];
  __shared__ float lp[32*8];
  __shared__ float att_s[32];
  int t = threadIdx.x, lane = t&63, w = t>>6;
  int R0 = blockIdx.x*32;

  // emb = tanh(accg) for our 32 rows
  for (int idx=t; idx<4096; idx+=256)
    bufE[idx] = f2h(tanh_fast(accg[(size_t)R0*128 + idx]));
  // mean_rep faithful ordering: row n pairs with mean[(n % 1024)]
  for (int idx=t; idx<512; idx+=256){
    int r = idx>>4, c8 = (idx&15)<<3;
    int n = R0 + r;
    *(uint4*)(bufM + r*128 + c8) = *(const uint4*)(mean16 + (size_t)(n & 1023)*128 + c8);
  }
  for (int idx=t; idx<512; idx+=256) fin[idx] = 0.f;
  __syncthreads();

  stage<8>(bufE, bufM, aw1t, ab1, bufA, w, lane);
  __syncthreads();
  stage<4>(bufA, nullptr, aw2t, ab2, bufM, w, lane);
  __syncthreads();
  {
    int r = t>>3, seg = t&7;
    float p = 0.f;
    const unsigned short* row = bufM + r*128 + seg*16;
    const float* w3 = aw3 + seg*16;
    #pragma unroll
    for (int k=0;k<16;++k) p += h2f(row[k]) * w3[k];
    lp[r*8+seg] = p;
  }
  __syncthreads();
  if (t < 4){
    float lg[8]; float mx = -1e30f;
    for (int l=0;l<8;++l){
      float s = ab3[0];
      #pragma unroll
      for (int sg=0;sg<8;++sg) s += lp[(t*8+l)*8+sg];
      lg[l] = s; mx = fmaxf(mx, s);
    }
    float sum = 0.f;
    for (int l=0;l<8;++l){ lg[l] = __builtin_amdgcn_exp2f((lg[l]-mx)*1.44269504089f); sum += lg[l]; }
    float inv = __builtin_amdgcn_rcpf(sum);
    for (int l=0;l<8;++l) att_s[t*8+l] = lg[l]*inv;
  }
  __syncthreads();
  stage<4>(bufE, nullptr, vw1t, vb1, bufA, w, lane);
  __syncthreads();
  {
    #pragma unroll
    for (int obl=0; obl<2; ++obl){
      int col = ((w*2+obl)<<4) + (lane&15);
      f32x4 a0 = {0.f,0.f,0.f,0.f}, a1v = {0.f,0.f,0.f,0.f};
      #pragma unroll
      for (int s=0;s<4;++s){
        f16x8 bfr = *(const f16x8*)(vw2t + (size_t)col*128 + s*32 + ((lane>>4)<<3));
        a0  = mfma16(ldsA(bufA,0,s,lane), bfr, a0);
        a1v = mfma16(ldsA(bufA,1,s,lane), bfr, a1v);
      }
      float bb = vb2[col];
      #pragma unroll
      for (int reg=0;reg<4;++reg){
        int r0 = ((lane>>4)<<2) + reg;
        float v0 = tanh_fast(a0[reg]+bb);
        float v1 = tanh_fast(a1v[reg]+bb);
        atomicAdd(&fin[((r0)>>3)*128 + col],    att_s[r0]    * v0);
        atomicAdd(&fin[((16+r0)>>3)*128 + col], att_s[16+r0] * v1);
      }
    }
  }
  __syncthreads();
  for (int idx=t; idx<512; idx+=256){
    int b_loc = idx>>7, o = idx&127;
    outp[(size_t)(R0/8 + b_loc)*128 + o] = fin[idx];
  }
}

// ---------- launch ----------
extern "C" void kernel_launch(void* const* d_in, const int* in_sizes, int n_in,
                              void* d_out, int out_size, void* d_ws, size_t ws_size,
                              hipStream_t stream){
  const float* obs = (const float*)d_in[0];
  const float* hw1 = (const float*)d_in[3];
  const float* hb1 = (const float*)d_in[4];
  const float* hw2 = (const float*)d_in[5];
  const float* hb2 = (const float*)d_in[6];
  const float* vw1 = (const float*)d_in[7];
  const float* vb1 = (const float*)d_in[8];
  const float* vw2 = (const float*)d_in[9];
  const float* vb2 = (const float*)d_in[10];
  const float* aw1 = (const float*)d_in[11];
  const float* ab1 = (const float*)d_in[12];
  const float* aw2 = (const float*)d_in[13];
  const float* ab2 = (const float*)d_in[14];
  const float* aw3 = (const float*)d_in[15];
  const float* ab3 = (const float*)d_in[16];

  char* ws = (char*)d_ws;
  unsigned short* wt2    = (unsigned short*)(ws);             // 3,145,728 B
  unsigned short* mean16 = (unsigned short*)(ws);             //   262,144 B (alias; wt2 dead after k2)
  unsigned short* h16    = (unsigned short*)(ws + 3145728);   // 2,097,152 B
  float*          accg   = (float*)        (ws + 5242880);    // 4,194,304 B
  unsigned short* vw1t   = (unsigned short*)(ws + 9437184);   //    32,768 B
  unsigned short* vw2t   = (unsigned short*)(ws + 9469952);   //    32,768 B
  unsigned short* aw1t   = (unsigned short*)(ws + 9502720);   //    65,536 B
  unsigned short* aw2t   = (unsigned short*)(ws + 9568256);   //    32,768 B  (end 9,601,024)
  float* outp = (float*)d_out;

  hipMemsetAsync(accg, 0, 8192*128*sizeof(float), stream);
  prep_kernel<<<1872, 256, 0, stream>>>(obs, hw1, hb1, hw2, vw1, vw2, aw1, aw2,
                                        wt2, vw1t, vw2t, aw1t, aw2t, h16);
  k2_hyper<<<256, 512, 0, stream>>>(obs, h16, wt2, hb2, accg);
  k3_mean<<<256, 256, 0, stream>>>(accg, mean16);
  k4_mlp<<<256, 256, 0, stream>>>(accg, mean16, vw1t, vw2t, aw1t, aw2t,
                                  vb1, vb2, ab1, ab2, aw3, ab3, outp);
}